// Round 1
// 157.334 us; speedup vs baseline: 1.1399x; 1.1399x over previous
//
#include <hip/hip_runtime.h>
#include <math.h>

#define D_FEAT 100
#define ROW_STRIDE 300     // 3 * D_FEAT concatenated output blocks
#define ROWQ 26            // table row = 26 qwords = 208 B:
                           //   qword 0 = {w:f32, 0.f}; qwords 1..25 = bf16x4 feats
#define ROWB 208u          // 208 = 13 * 16  -> dwordx4-aligned sub-blocks

// ---------------------------------------------------------------------------
// fast tanh via hardware exp (inputs bounded, |2x| <= ~12)
// ---------------------------------------------------------------------------
__device__ __forceinline__ float fast_tanh(float x) {
    float ax = fabsf(x);
    float e  = __expf(2.f * ax);
    float t  = 1.f - 2.f / (e + 1.f);
    return copysignf(t, x);
}

// bf16 packing (RNE)
__device__ __forceinline__ unsigned pack_bf16x2(float a, float b) {
    unsigned ua = __float_as_uint(a);
    unsigned ub = __float_as_uint(b);
    ua += 0x7fffu + ((ua >> 16) & 1u);
    ub += 0x7fffu + ((ub >> 16) & 1u);
    return (ua >> 16) | (ub & 0xffff0000u);
}
__device__ __forceinline__ unsigned long long pack_bf16x4(float a, float b,
                                                          float c, float d) {
    return (unsigned long long)pack_bf16x2(a, b) |
           ((unsigned long long)pack_bf16x2(c, d) << 32);
}
__device__ __forceinline__ void unpack_bf16x4(unsigned long long u,
                                              float& x0, float& x1,
                                              float& x2, float& x3) {
    unsigned lo = (unsigned)u, hi = (unsigned)(u >> 32);
    x0 = __uint_as_float(lo << 16);
    x1 = __uint_as_float(lo & 0xffff0000u);
    x2 = __uint_as_float(hi << 16);
    x3 = __uint_as_float(hi & 0xffff0000u);
}
__device__ __forceinline__ void unpack2(unsigned u, float& lo, float& hi) {
    lo = __uint_as_float(u << 16);
    hi = __uint_as_float(u & 0xffff0000u);
}

// butterfly sum within each 32-lane half
__device__ __forceinline__ float half_reduce(float v) {
    #pragma unroll
    for (int off = 16; off; off >>= 1) v += __shfl_xor(v, off, 64);
    return v;
}

// ---------------------------------------------------------------------------
// Kernel 1: 2 nodes per wave + fused CSR binary search.  (unchanged)
// Lane convention (shifted): lanes 1..25 hold elems 4(l-1)..4(l-1)+3.
// ---------------------------------------------------------------------------
__global__ __launch_bounds__(256) void tanh_score_kernel(
    const float* __restrict__ features,
    float* __restrict__ out,
    unsigned long long* __restrict__ tab0,   // 208-B-row table or null
    float* __restrict__ escore0,             // fallback score array
    const float* __restrict__ none_rel,
    const int* __restrict__ adj,
    int* __restrict__ startArr,
    int E, int N)
{
    int gtid = blockIdx.x * blockDim.x + threadIdx.x;
    if (gtid <= N) {                          // fused CSR
        if (gtid == N) startArr[N] = E;
        else {
            int lo = 0, hi = E;
            while (lo < hi) {
                int mid = (lo + hi) >> 1;
                if (adj[2 * mid] < gtid) lo = mid + 1; else hi = mid;
            }
            startArr[gtid] = lo;
        }
    }

    int waveId = gtid >> 6;
    int lane = threadIdx.x & 63;
    int half = lane >> 5;
    int l    = lane & 31;
    int n    = waveId * 2 + half;
    const bool valid_n = (n < N);
    const bool fact = valid_n && (l >= 1) && (l <= 25);

    float x0 = 0.f, x1 = 0.f, x2 = 0.f, x3 = 0.f;
    if (fact) {
        float4 f = ((const float4*)(features + (size_t)n * D_FEAT))[l - 1];
        x0 = fast_tanh(f.x); x1 = fast_tanh(f.y);
        x2 = fast_tanh(f.z); x3 = fast_tanh(f.w);
        ((float4*)(out + (size_t)n * ROW_STRIDE))[l - 1] = make_float4(x0, x1, x2, x3);
        if (tab0) tab0[(size_t)n * ROWQ + l] = pack_bf16x4(x0, x1, x2, x3);
    }

    float nx = 0.f, ny = 0.f, nz = 0.f, nw = 0.f;
    if (l >= 1 && l <= 25) {
        float4 v = ((const float4*)none_rel)[l - 1];
        nx = v.x; ny = v.y; nz = v.z; nw = v.w;
    }
    float ss = half_reduce(nx * nx + ny * ny + nz * nz + nw * nw);
    float inv_nr = 1.f / fmaxf(sqrtf(ss), 1e-12f);

    float dot = half_reduce(x0 * nx + x1 * ny + x2 * nz + x3 * nw) * inv_nr;
    float sq  = half_reduce(x0 * x0 + x1 * x1 + x2 * x2 + x3 * x3);
    if (l == 0 && valid_n) {
        float es = __expf(-dot / fmaxf(sqrtf(sq), 1e-12f));
        if (tab0) tab0[(size_t)n * ROWQ] = (unsigned long long)__float_as_uint(es);
        else      escore0[n] = es;
    }
}

// ---------------------------------------------------------------------------
// Kernel 2 (new): fused attention layer, 2 nodes per wave, 16-B row loads.
//  A 208-B row is 13 x dwordx4. Lanes 0..12 fetch row of edge i, lanes 13..25
//  row of edge i+1 -> 2 edges per half per pass, 4 per wave pass.
//  One ds_bpermute delivers both cols (per-lane src index), one more both
//  weights. Even/odd-edge partial sums are combined with 9 bpermutes at the
//  end. No exec-masked loads: invalid edges read row 0, weight is cndmask'd.
//  Lane mapping (per 32-half): wh = (13<=l<26), sub = l - 13*wh  (l>=26 idle)
//    sub==0 : dwords {w, 0, f0..f3}   -> acc slots 4..7 hold feats 0..3
//    sub>=1 : feats 8*sub-4 .. 8*sub+3 in acc slots 0..7
// ---------------------------------------------------------------------------
template <bool WRITE_TAB>
__global__ __launch_bounds__(256) void attn16_kernel(
    const unsigned long long* __restrict__ tab,   // prev 208-B table
    float* __restrict__ outp,
    unsigned long long* __restrict__ tab_out,     // next table (or unused)
    const int2* __restrict__ adj2,
    const int* __restrict__ start,
    const float* __restrict__ none_rel,
    int N)
{
    const int waveId = (int)((blockIdx.x * blockDim.x + threadIdx.x) >> 6);
    const int lane = threadIdx.x & 63;
    const int half = lane >> 5;
    const int l    = lane & 31;
    const int base = half << 5;
    const int n    = waveId * 2 + half;
    const bool valid_n = (n < N);

    const bool act  = (l < 26);
    const int  wh   = (act && l >= 13) ? 1 : 0;   // which edge of the pair
    const int  sub  = act ? (l - 13 * wh) : 0;    // 16-B block within row
    const bool actA = (l < 13);                   // lanes holding final output

    int e0 = 0, e1 = 0;
    if (valid_n) { e0 = start[n]; e1 = start[n + 1]; }
    const int deg = e1 - e0;
    int maxdeg = deg;
    { int o = __shfl_xor(maxdeg, 32, 64); maxdeg = maxdeg > o ? maxdeg : o; }

    // stage cols for up to 64 edges (lane l of half holds col of edge l)
    int c0 = 0, c1 = 0;
    if (l < deg)      c0 = adj2[e0 + l].y;
    if (l + 32 < deg) c1 = adj2[e0 + l + 32].y;

    const char* tb = (const char*)tab;
    const size_t suboff = (size_t)(sub * 16);
    const int wsrc = base + 13 * wh;     // lane whose v.x is this group's w
    const int degw = deg - wh;           // pair-base i valid iff i < degw

    float a0=0.f,a1=0.f,a2=0.f,a3=0.f,a4=0.f,a5=0.f,a6=0.f,a7=0.f;
    float d_acc = 0.f;

#define ATTN16_PASS(CSTAGE, I, SRC)                                           \
    {                                                                         \
        int c = __shfl((CSTAGE), base + (SRC) + wh, 64);                      \
        const uint4 v = *(const uint4*)(tb + (size_t)(unsigned)c * ROWB + suboff); \
        float w = __shfl(__uint_as_float(v.x), wsrc, 64);                     \
        w = ((I) < degw) ? w : 0.f;                                           \
        float p0,p1,p2,p3,p4,p5,p6,p7;                                        \
        unpack2(v.x,p0,p1); unpack2(v.y,p2,p3);                               \
        unpack2(v.z,p4,p5); unpack2(v.w,p6,p7);                               \
        if (sub == 0) { p0 = 0.f; p1 = 0.f; }    /* qword0 = {w,pad} */       \
        a0 += w*p0; a1 += w*p1; a2 += w*p2; a3 += w*p3;                       \
        a4 += w*p4; a5 += w*p5; a6 += w*p6; a7 += w*p7;                       \
        d_acc += w;                                                           \
    }

    const int cap1 = maxdeg < 32 ? maxdeg : 32;
    for (int r = 0; r < cap1; r += 8) {          // 8 edges = 4 passes
        #pragma unroll
        for (int j = 0; j < 4; ++j) {
            const int i = r + 2 * j;
            ATTN16_PASS(c0, i, i)
        }
    }
    const int cap2 = maxdeg < 64 ? maxdeg : 64;
    for (int r = 32; r < cap2; r += 8) {
        #pragma unroll
        for (int j = 0; j < 4; ++j) {
            const int i = r + 2 * j;
            ATTN16_PASS(c1, i, i - 32)
        }
    }
#undef ATTN16_PASS

    // deg > 64 tail (~never): one edge per pass, group A accumulates
    for (int e = e0 + 64; e < e1; ++e) {
        int c = adj2[e].y;
        const uint4 v = *(const uint4*)(tb + (size_t)(unsigned)c * ROWB + suboff);
        float w = __shfl(__uint_as_float(v.x), base, 64);
        float p0,p1,p2,p3,p4,p5,p6,p7;
        unpack2(v.x,p0,p1); unpack2(v.y,p2,p3);
        unpack2(v.z,p4,p5); unpack2(v.w,p6,p7);
        if (sub == 0) { p0 = 0.f; p1 = 0.f; }
        if (wh == 0) {
            a0 += w*p0; a1 += w*p1; a2 += w*p2; a3 += w*p3;
            a4 += w*p4; a5 += w*p5; a6 += w*p6; a7 += w*p7;
            d_acc += w;
        }
    }

    // ---- combine even/odd edge groups (lane l <-> lane l+-13) ----
    const int partner = base + (actA ? l + 13 : (act ? l - 13 : l));
    d_acc += __shfl(d_acc, partner, 64);
    a0 += __shfl(a0, partner, 64);
    a1 += __shfl(a1, partner, 64);
    a2 += __shfl(a2, partner, 64);
    a3 += __shfl(a3, partner, 64);
    a4 += __shfl(a4, partner, 64);
    a5 += __shfl(a5, partner, 64);
    a6 += __shfl(a6, partner, 64);
    a7 += __shfl(a7, partner, 64);

    const float inv_d = (deg > 0) ? 1.f / d_acc : 0.f;
    float r0 = fast_tanh(a0 * inv_d);
    float r1 = fast_tanh(a1 * inv_d);
    float r2 = fast_tanh(a2 * inv_d);
    float r3 = fast_tanh(a3 * inv_d);
    float r4 = fast_tanh(a4 * inv_d);
    float r5 = fast_tanh(a5 * inv_d);
    float r6 = fast_tanh(a6 * inv_d);
    float r7 = fast_tanh(a7 * inv_d);
    if (!actA) { r0=r1=r2=r3=r4=r5=r6=r7=0.f; }   // avoid double-count in reduces

    // ---- writes: f32 out (+ bf16 table) ----
    if (valid_n && actA) {
        float4* orow = (float4*)(outp + (size_t)n * ROW_STRIDE);
        if (l == 0) {
            orow[0] = make_float4(r4, r5, r6, r7);            // feats 0..3
        } else {
            orow[2*l - 1] = make_float4(r0, r1, r2, r3);      // feats 8l-4..8l-1
            orow[2*l]     = make_float4(r4, r5, r6, r7);      // feats 8l..8l+3
        }
        if constexpr (WRITE_TAB) {
            if (l > 0) {
                uint4* trow = (uint4*)((char*)tab_out + (size_t)n * ROWB);
                trow[l] = make_uint4(pack_bf16x2(r0,r1), pack_bf16x2(r2,r3),
                                     pack_bf16x2(r4,r5), pack_bf16x2(r6,r7));
            }
        }
    }

    // ---- epilogue: next layer's exp-score (only when another layer follows) ----
    if constexpr (WRITE_TAB) {
        float n0=0.f,n1=0.f,n2=0.f,n3=0.f,n4=0.f,n5=0.f,n6=0.f,n7=0.f;
        if (l == 0) {
            float4 v = ((const float4*)none_rel)[0];
            n4=v.x; n5=v.y; n6=v.z; n7=v.w;
        } else if (l < 13) {
            float4 u = *(const float4*)(none_rel + 8*l - 4);
            float4 v = *(const float4*)(none_rel + 8*l);
            n0=u.x; n1=u.y; n2=u.z; n3=u.w;
            n4=v.x; n5=v.y; n6=v.z; n7=v.w;
        }
        float ss = half_reduce(n0*n0+n1*n1+n2*n2+n3*n3+n4*n4+n5*n5+n6*n6+n7*n7);
        float inv_nr = 1.f / fmaxf(sqrtf(ss), 1e-12f);
        float dot = half_reduce(r0*n0+r1*n1+r2*n2+r3*n3+r4*n4+r5*n5+r6*n6+r7*n7) * inv_nr;
        float sq  = half_reduce(r0*r0+r1*r1+r2*r2+r3*r3+r4*r4+r5*r5+r6*r6+r7*r7);
        if (l == 0 && valid_n) {
            float es = __expf(-dot / fmaxf(sqrtf(sq), 1e-12f));
            uint4* trow = (uint4*)((char*)tab_out + (size_t)n * ROWB);
            trow[0] = make_uint4(__float_as_uint(es), 0u,
                                 pack_bf16x2(r4,r5), pack_bf16x2(r6,r7));
        }
    }
}

// ---------------------------------------------------------------------------
// Fallback attention kernel (f32 path, only used when workspace is too small
// for the bf16 tables).  Unchanged from previous version.
// ---------------------------------------------------------------------------
template <bool TAB>
__global__ __launch_bounds__(256) void attn_kernel(
    const void* __restrict__ prev,           // f32 stride-300
    float* __restrict__ outp,
    unsigned long long* __restrict__ tab_out,
    const int2* __restrict__ adj2,
    const int* __restrict__ start,
    const float* __restrict__ escore_in,
    float* __restrict__ escore_out,
    const float* __restrict__ none_rel,
    int N)
{
    int waveId = (int)((blockIdx.x * blockDim.x + threadIdx.x) >> 6);
    int lane = threadIdx.x & 63;
    int half = lane >> 5;
    int l    = lane & 31;
    int n    = waveId * 2 + half;
    const bool valid_n = (n < N);
    const bool fact = valid_n && (l >= 1) && (l <= 25);
    const int base = half << 5;

    int e0 = 0, e1 = 0;
    if (valid_n) { e0 = start[n]; e1 = start[n + 1]; }
    const int deg = e1 - e0;

    int   c0 = 0, c1 = 0;
    float w0 = 0.f, w1 = 0.f;
    if (l < deg)      { c0 = adj2[e0 + l].y;      if (!TAB) w0 = escore_in[c0]; }
    if (l + 32 < deg) { c1 = adj2[e0 + l + 32].y; if (!TAB) w1 = escore_in[c1]; }

    int maxdeg = deg;
    { int o = __shfl_xor(maxdeg, 32, 64); maxdeg = maxdeg > o ? maxdeg : o; }

    const float* pf32 = (const float*)prev;

    float d_acc = 0.f, a0 = 0.f, a1 = 0.f, a2 = 0.f, a3 = 0.f;
    const int cap1 = maxdeg < 32 ? maxdeg : 32;
    for (int r = 0; r < cap1; r += 8) {
        #pragma unroll
        for (int j = 0; j < 8; ++j) {
            int   i = r + j;
            int   c = __shfl(c0, base + i, 64);
            float w = __shfl(w0, base + i, 64);
            float p0 = 0.f, p1 = 0.f, p2 = 0.f, p3 = 0.f;
            if (fact && (i < deg)) {
                float4 v = ((const float4*)(pf32 + (size_t)c * ROW_STRIDE))[l - 1];
                p0 = v.x; p1 = v.y; p2 = v.z; p3 = v.w;
            }
            if (i >= deg) w = 0.f;
            d_acc += w;
            a0 += w * p0; a1 += w * p1; a2 += w * p2; a3 += w * p3;
        }
    }
    const int cap2 = maxdeg < 64 ? maxdeg : 64;
    for (int r = 32; r < cap2; r += 8) {
        #pragma unroll
        for (int j = 0; j < 8; ++j) {
            int   i = r + j;
            int   c = __shfl(c1, base + i - 32, 64);
            float w = __shfl(w1, base + i - 32, 64);
            float p0 = 0.f, p1 = 0.f, p2 = 0.f, p3 = 0.f;
            if (fact && (i < deg)) {
                float4 v = ((const float4*)(pf32 + (size_t)c * ROW_STRIDE))[l - 1];
                p0 = v.x; p1 = v.y; p2 = v.z; p3 = v.w;
            }
            if (i >= deg) w = 0.f;
            d_acc += w;
            a0 += w * p0; a1 += w * p1; a2 += w * p2; a3 += w * p3;
        }
    }
    for (int e = e0 + 64; e < e1; ++e) {
        int c = adj2[e].y;
        float w = escore_in[c];
        float p0 = 0.f, p1 = 0.f, p2 = 0.f, p3 = 0.f;
        if (fact) {
            float4 v = ((const float4*)(pf32 + (size_t)c * ROW_STRIDE))[l - 1];
            p0 = v.x; p1 = v.y; p2 = v.z; p3 = v.w;
        }
        d_acc += w;
        a0 += w * p0; a1 += w * p1; a2 += w * p2; a3 += w * p3;
    }

    const float inv_d = (deg > 0) ? 1.f / d_acc : 0.f;
    float r0 = fast_tanh(a0 * inv_d);
    float r1 = fast_tanh(a1 * inv_d);
    float r2 = fast_tanh(a2 * inv_d);
    float r3 = fast_tanh(a3 * inv_d);
    if (fact) {
        ((float4*)(outp + (size_t)n * ROW_STRIDE))[l - 1] = make_float4(r0, r1, r2, r3);
    } else {
        r0 = r1 = r2 = r3 = 0.f;
    }

    if (escore_out) {
        float nx = 0.f, ny = 0.f, nz = 0.f, nw = 0.f;
        if (l >= 1 && l <= 25) {
            float4 v = ((const float4*)none_rel)[l - 1];
            nx = v.x; ny = v.y; nz = v.z; nw = v.w;
        }
        float ss = half_reduce(nx * nx + ny * ny + nz * nz + nw * nw);
        float inv_nr = 1.f / fmaxf(sqrtf(ss), 1e-12f);
        float dot = half_reduce(r0 * nx + r1 * ny + r2 * nz + r3 * nw) * inv_nr;
        float sq  = half_reduce(r0 * r0 + r1 * r1 + r2 * r2 + r3 * r3);
        if (l == 0 && valid_n) {
            float es = __expf(-dot / fmaxf(sqrtf(sq), 1e-12f));
            escore_out[n] = es;
        }
    }
}

// ---------------------------------------------------------------------------
extern "C" void kernel_launch(void* const* d_in, const int* in_sizes, int n_in,
                              void* d_out, int out_size, void* d_ws, size_t ws_size,
                              hipStream_t stream) {
    const float* features = (const float*)d_in[0];
    // d_in[1] = rel_emb: unused by the reference
    const int*   adj      = (const int*)d_in[2];
    const float* none_rel = (const float*)d_in[3];
    float* out = (float*)d_out;

    const int N = in_sizes[0] / D_FEAT;   // 50000
    const int E = in_sizes[2] / 2;        // 800000

    // ws: start[N+1] | escore0[N] | escore1[N] | tab0[N*26 u64] | tab1[N*26 u64]
    size_t off = 0;
    auto take = [&](size_t bytes) { size_t o = off; off = (off + bytes + 15) & ~(size_t)15; return o; };
    char* w = (char*)d_ws;
    int*   start   = (int*)  (w + take(sizeof(int)   * (size_t)(N + 1)));
    float* escore0 = (float*)(w + take(sizeof(float) * (size_t)N));
    float* escore1 = (float*)(w + take(sizeof(float) * (size_t)N));
    size_t tab_off0 = take(sizeof(unsigned long long) * (size_t)N * ROWQ);
    size_t tab_off1 = take(sizeof(unsigned long long) * (size_t)N * ROWQ);
    const bool use_tab = (ws_size >= off);
    unsigned long long* tab0 = use_tab ? (unsigned long long*)(w + tab_off0) : nullptr;
    unsigned long long* tab1 = use_tab ? (unsigned long long*)(w + tab_off1) : nullptr;

    const int pairs = (N + 1) / 2;                       // 2 nodes per wave
    const int node_blocks = (pairs * 64 + 255) / 256;
    const int2* adj2 = (const int2*)adj;

    tanh_score_kernel<<<node_blocks, 256, 0, stream>>>(features, out, tab0,
                                                       escore0, none_rel,
                                                       adj, start, E, N);
    if (use_tab) {
        attn16_kernel<true><<<node_blocks, 256, 0, stream>>>(
            tab0, out + D_FEAT, tab1, adj2, start, none_rel, N);
        attn16_kernel<false><<<node_blocks, 256, 0, stream>>>(
            tab1, out + 2 * D_FEAT, nullptr, adj2, start, none_rel, N);
    } else {
        attn_kernel<false><<<node_blocks, 256, 0, stream>>>(
            out, out + D_FEAT, nullptr, adj2, start, escore0, escore1, none_rel, N);
        attn_kernel<false><<<node_blocks, 256, 0, stream>>>(
            out + D_FEAT, out + 2 * D_FEAT, nullptr, adj2, start, escore1, nullptr, none_rel, N);
    }
}